// Round 3
// baseline (11.989 us; speedup 1.0000x reference)
//
#include <hip/hip_runtime.h>

#define B_ 8
#define C_ 64
#define N_ 4096
#define K_ 16
#define THREADS 512
#define NQ 4                          // node quarters per (batch, channel-quad)
#define NODES_PER_BLK (N_ / NQ)       // 1024
#define NPT (NODES_PER_BLK / THREADS) // 2 nodes per thread

// LDS slot swizzle: spreads ds_write_b128 start-banks over all 8 quad
// positions (else lane-consecutive float4 writes all start at bank 0/16).
// Bijective on [0,4096): XORs bits 0-2 with bits 3-5.
__device__ __forceinline__ int slot(int n) { return n ^ ((n >> 3) & 7); }

// One block per (batch, channel-quad, node-quarter).
// Stage all 4096 nodes x 4 channels as float4 in LDS (64 KB, swizzled),
// gather 16 neighbors per node with ds_read_b128, fused write-out.
__global__ __launch_bounds__(THREADS) void fused_k(const float* __restrict__ x,
                                                   const int* __restrict__ ei,
                                                   const float* __restrict__ alpha_p,
                                                   float* __restrict__ out) {
  __shared__ float4 xs[N_];           // 64 KB
  const int bid = blockIdx.x;         // 512 = 8 b * 16 cq * 4 nq
  const int b   = bid & 7;            // batch on low bits -> per-XCD x/ei locality
  const int cq  = (bid >> 3) & 15;
  const int nq  = bid >> 7;
  const int c0  = cq * 4;
  const int n0  = nq * NODES_PER_BLK;
  const int t   = threadIdx.x;

  // Prefetch this thread's edge ids first (hides L2/HBM latency under staging).
  int idx[NPT][K_];
  const int* eib = ei + ((size_t)b * N_ + n0) * K_;
#pragma unroll
  for (int q = 0; q < NPT; ++q) {
    const int4* ep = reinterpret_cast<const int4*>(eib + (size_t)(t + q * THREADS) * K_);
    *reinterpret_cast<int4*>(&idx[q][0])  = ep[0];
    *reinterpret_cast<int4*>(&idx[q][4])  = ep[1];
    *reinterpret_cast<int4*>(&idx[q][8])  = ep[2];
    *reinterpret_cast<int4*>(&idx[q][12]) = ep[3];
  }

  // Stage: 4 coalesced float4 row-loads per nodegroup, 4x4 register transpose,
  // 4 ds_write_b128 at swizzled slots.
  const float* xb = x + ((size_t)b * C_ + c0) * N_;
#pragma unroll
  for (int g = 0; g < N_ / (4 * THREADS); ++g) {  // 2 nodegroups of 4 nodes
    const int j = t + g * THREADS;
    const float4 r0 = *reinterpret_cast<const float4*>(xb + 0 * N_ + 4 * j);
    const float4 r1 = *reinterpret_cast<const float4*>(xb + 1 * N_ + 4 * j);
    const float4 r2 = *reinterpret_cast<const float4*>(xb + 2 * N_ + 4 * j);
    const float4 r3 = *reinterpret_cast<const float4*>(xb + 3 * N_ + 4 * j);
    xs[slot(4 * j + 0)] = make_float4(r0.x, r1.x, r2.x, r3.x);
    xs[slot(4 * j + 1)] = make_float4(r0.y, r1.y, r2.y, r3.y);
    xs[slot(4 * j + 2)] = make_float4(r0.z, r1.z, r2.z, r3.z);
    xs[slot(4 * j + 3)] = make_float4(r0.w, r1.w, r2.w, r3.w);
  }
  __syncthreads();

  const float s = 1.0f + alpha_p[0];
#pragma unroll
  for (int q = 0; q < NPT; ++q) {
    const int n = n0 + t + q * THREADS;
    float4 acc = make_float4(0.f, 0.f, 0.f, 0.f);
#pragma unroll
    for (int k = 0; k < K_; ++k) {
      const float4 v = xs[slot(idx[q][k])];   // ds_read_b128
      acc.x += v.x; acc.y += v.y; acc.z += v.z; acc.w += v.w;
    }
    const float4 sv = xs[slot(n)];            // self term from LDS
    const size_t o = (size_t)(b * C_ + c0) * N_ + n;
    out[o + 0 * N_] = sv.x * s + acc.x;
    out[o + 1 * N_] = sv.y * s + acc.y;
    out[o + 2 * N_] = sv.z * s + acc.z;
    out[o + 3 * N_] = sv.w * s + acc.w;
  }
}

extern "C" void kernel_launch(void* const* d_in, const int* in_sizes, int n_in,
                              void* d_out, int out_size, void* d_ws, size_t ws_size,
                              hipStream_t stream) {
  const float* x     = (const float*)d_in[0];
  const int*   ei    = (const int*)d_in[1];
  const float* alpha = (const float*)d_in[2];
  float*       out   = (float*)d_out;
  (void)d_ws; (void)ws_size;

  fused_k<<<B_ * (C_ / 4) * NQ, THREADS, 0, stream>>>(x, ei, alpha, out);
}